// Round 1
// baseline (723.382 us; speedup 1.0000x reference)
//
#include <hip/hip_runtime.h>

// B=16384, T=56, F=56, H=20, 3H=60, FC1=128, NC=2
// Design: one wave per batch element; lanes 0..59 = the 60 gate rows (r,z,n x H).
// Weights register-resident per lane (~116 VGPRs). x loads are wave-uniform.
// h-state broadcast via v_readlane -> scalar operands for the recurrent dots.
// fc2(fc1(.)) collapsed to W_eff [1120,2] (no nonlinearity between them),
// accumulated on the fly; h1/h2 never hit HBM.

#define Bsz  16384
#define Tt   56
#define Ff   56
#define Hh   20
#define Gg   60
#define FC1n 128
#define THn  1120  // T*H

__device__ __forceinline__ float rdlane(float v, int l) {
  return __uint_as_float(__builtin_amdgcn_readlane(__float_as_uint(v), l));
}
__device__ __forceinline__ float fast_rcp(float x) { return __builtin_amdgcn_rcpf(x); }
__device__ __forceinline__ float sigmoid_fast(float x) { return fast_rcp(1.0f + __expf(-x)); }
// tanh(x) = 1 - 2/(exp(2x)+1); exp->inf and exp->0 both give correct limits.
__device__ __forceinline__ float tanh_fast(float x) { return 1.0f - 2.0f * fast_rcp(1.0f + __expf(2.0f * x)); }

// W_eff[i][c] = sum_j W_fc1[j,i] * W_fc2[c,j];  b_eff[c] = b_fc2[c] + sum_j b_fc1[j]*W_fc2[c,j]
__global__ void prep_weff(const float* __restrict__ Wfc1, const float* __restrict__ bfc1,
                          const float* __restrict__ Wfc2, const float* __restrict__ bfc2,
                          float* __restrict__ ws) {
  int i = blockIdx.x * blockDim.x + threadIdx.x;
  if (i < THn) {
    float s0 = 0.f, s1 = 0.f;
    for (int j = 0; j < FC1n; ++j) {
      float w = Wfc1[j * THn + i];
      s0 = fmaf(w, Wfc2[j], s0);
      s1 = fmaf(w, Wfc2[FC1n + j], s1);
    }
    ws[i * 2 + 0] = s0;
    ws[i * 2 + 1] = s1;
  } else if (i < THn + 2) {
    int c = i - THn;
    float s = bfc2[c];
    for (int j = 0; j < FC1n; ++j) s = fmaf(bfc1[j], Wfc2[c * FC1n + j], s);
    ws[2 * THn + c] = s;
  }
}

__global__ __launch_bounds__(256) void gru_scan(
    const float* __restrict__ x,
    const float* __restrict__ Wih0, const float* __restrict__ Whh0,
    const float* __restrict__ bih0, const float* __restrict__ bhh0,
    const float* __restrict__ Wih1, const float* __restrict__ Whh1,
    const float* __restrict__ bih1, const float* __restrict__ bhh1,
    const float* __restrict__ ws, float* __restrict__ y) {
  __shared__ float weff[2 * THn];
  for (int idx = threadIdx.x; idx < 2 * THn; idx += 256) weff[idx] = ws[idx];
  __syncthreads();

  const int lane = threadIdx.x & 63;
  const int wv = __builtin_amdgcn_readfirstlane(threadIdx.x >> 6);  // force SGPR -> uniform x addr
  const int b = blockIdx.x * 4 + wv;
  const int g = (lane < Gg) ? lane : 0;  // idle lanes 60..63 replicate row 0 (harmless)

  // register-resident weight rows for this lane's gate
  float wih0[Ff], whh0[Hh], wih1[Hh], whh1[Hh];
#pragma unroll
  for (int f = 0; f < Ff; ++f) wih0[f] = Wih0[g * Ff + f];
#pragma unroll
  for (int k = 0; k < Hh; ++k) whh0[k] = Whh0[g * Hh + k];
#pragma unroll
  for (int k = 0; k < Hh; ++k) wih1[k] = Wih1[g * Hh + k];
#pragma unroll
  for (int k = 0; k < Hh; ++k) whh1[k] = Whh1[g * Hh + k];
  const float bi0 = bih0[g], bh0 = bhh0[g], bi1 = bih1[g], bh1 = bhh1[g];

  // broadcast h-state (uniform scalars) + per-lane owned h (lane 40+j owns h[j])
  float sA[Hh], sB[Hh];
#pragma unroll
  for (int k = 0; k < Hh; ++k) { sA[k] = 0.f; sB[k] = 0.f; }
  float hmA = 0.f, hmB = 0.f, y0 = 0.f, y1 = 0.f;

  const float* xrow = x + (size_t)b * (Tt * Ff);
  const int srcR = (lane >= 40) ? lane - 40 : lane;  // n-lane 40+j pulls r from lane j
  const int srcZ = (lane >= 40) ? lane - 20 : lane;  // n-lane 40+j pulls z from lane 20+j
  const int jm = (lane >= 40 && lane < Gg) ? lane - 40 : 0;

#pragma unroll 1
  for (int t = 0; t < Tt; ++t) {
    // ---- layer 0 ----
    {
      float a0 = bi0, a1 = 0.f, a2 = 0.f, a3 = 0.f;
#pragma unroll
      for (int f = 0; f < Ff; f += 4) {
        a0 = fmaf(xrow[f + 0], wih0[f + 0], a0);
        a1 = fmaf(xrow[f + 1], wih0[f + 1], a1);
        a2 = fmaf(xrow[f + 2], wih0[f + 2], a2);
        a3 = fmaf(xrow[f + 3], wih0[f + 3], a3);
      }
      float ig = (a0 + a1) + (a2 + a3);
      float h0 = bh0, h1v = 0.f;
#pragma unroll
      for (int k = 0; k < Hh; k += 2) {
        h0 = fmaf(sA[k + 0], whh0[k + 0], h0);
        h1v = fmaf(sA[k + 1], whh0[k + 1], h1v);
      }
      float hg = h0 + h1v;
      float sg = sigmoid_fast(ig + hg);       // r on lanes 0..19, z on 20..39
      float rr = __shfl(sg, srcR, 64);
      float nn = tanh_fast(fmaf(rr, hg, ig)); // meaningful on lanes 40..59
      float zz = __shfl(sg, srcZ, 64);
      hmA = fmaf(zz, hmA - nn, nn);           // n + z*(h-n) == (1-z)*n + z*h
#pragma unroll
      for (int j = 0; j < Hh; ++j) sA[j] = rdlane(hmA, 40 + j);
    }
    // ---- layer 1 ----
    {
      float a0 = bi1, a1 = 0.f;
#pragma unroll
      for (int k = 0; k < Hh; k += 2) {
        a0 = fmaf(sA[k + 0], wih1[k + 0], a0);
        a1 = fmaf(sA[k + 1], wih1[k + 1], a1);
      }
      float ig = a0 + a1;
      float h0 = bh1, h1v = 0.f;
#pragma unroll
      for (int k = 0; k < Hh; k += 2) {
        h0 = fmaf(sB[k + 0], whh1[k + 0], h0);
        h1v = fmaf(sB[k + 1], whh1[k + 1], h1v);
      }
      float hg = h0 + h1v;
      float sg = sigmoid_fast(ig + hg);
      float rr = __shfl(sg, srcR, 64);
      float nn = tanh_fast(fmaf(rr, hg, ig));
      float zz = __shfl(sg, srcZ, 64);
      hmB = fmaf(zz, hmB - nn, nn);
#pragma unroll
      for (int j = 0; j < Hh; ++j) sB[j] = rdlane(hmB, 40 + j);
    }
    // ---- FC accumulation (lane 40+j holds h2[t][j]) ----
    {
      float2 wv2 = *(const float2*)&weff[(t * Hh + jm) * 2];
      y0 = fmaf(hmB, wv2.x, y0);
      y1 = fmaf(hmB, wv2.y, y1);
    }
    xrow += Ff;
  }

  // reduce the 20 n-lanes' partial FC sums across the wave
  if (!(lane >= 40 && lane < Gg)) { y0 = 0.f; y1 = 0.f; }
#pragma unroll
  for (int off = 32; off >= 1; off >>= 1) {
    y0 += __shfl_xor(y0, off, 64);
    y1 += __shfl_xor(y1, off, 64);
  }
  if (lane == 0) {
    float be0 = ws[2 * THn + 0], be1 = ws[2 * THn + 1];
    float2 out = make_float2(y0 + be0, y1 + be1);
    *(float2*)(y + (size_t)b * 2) = out;
  }
}

extern "C" void kernel_launch(void* const* d_in, const int* in_sizes, int n_in,
                              void* d_out, int out_size, void* d_ws, size_t ws_size,
                              hipStream_t stream) {
  const float* x    = (const float*)d_in[0];
  const float* Wih0 = (const float*)d_in[1];
  const float* Whh0 = (const float*)d_in[2];
  const float* bih0 = (const float*)d_in[3];
  const float* bhh0 = (const float*)d_in[4];
  const float* Wih1 = (const float*)d_in[5];
  const float* Whh1 = (const float*)d_in[6];
  const float* bih1 = (const float*)d_in[7];
  const float* bhh1 = (const float*)d_in[8];
  const float* Wfc1 = (const float*)d_in[9];
  const float* bfc1 = (const float*)d_in[10];
  const float* Wfc2 = (const float*)d_in[11];
  const float* bfc2 = (const float*)d_in[12];
  float* ws = (float*)d_ws;   // [2*1120 W_eff + 2 b_eff] floats
  float* y  = (float*)d_out;  // [16384, 2]

  prep_weff<<<9, 128, 0, stream>>>(Wfc1, bfc1, Wfc2, bfc2, ws);
  gru_scan<<<Bsz / 4, 256, 0, stream>>>(x, Wih0, Whh0, bih0, bhh0,
                                        Wih1, Whh1, bih1, bhh1, ws, y);
}

// Round 2
// 652.551 us; speedup vs baseline: 1.1085x; 1.1085x over previous
//
#include <hip/hip_runtime.h>

// B=16384, T=56, F=56, H=20, 3H=60, FC1=128, NC=2
// One wave per batch element; lanes 0..59 = the 60 gate rows (r,z,n x H).
// R2 change: x rows staged 1 step ahead via global_load_lds (async HBM->LDS,
// no VGPR cost), consumed with uniform-address ds_read_b128. Manual
// s_waitcnt vmcnt(1) expresses "previous row landed" (no other in-loop VMEM).
// h broadcast stays readlane->SGPR (keeps VGPR ~100 -> 5 waves/SIMD).

#define Bsz  16384
#define Tt   56
#define Ff   56
#define Hh   20
#define Gg   60
#define FC1n 128
#define THn  1120  // T*H

typedef __attribute__((address_space(1))) const unsigned char gas_uchar;
typedef __attribute__((address_space(3))) unsigned char las_uchar;

__device__ __forceinline__ float rdlane(float v, int l) {
  return __uint_as_float(__builtin_amdgcn_readlane(__float_as_uint(v), l));
}
__device__ __forceinline__ float fast_rcp(float x) { return __builtin_amdgcn_rcpf(x); }
__device__ __forceinline__ float sigmoid_fast(float x) { return fast_rcp(1.0f + __expf(-x)); }
__device__ __forceinline__ float tanh_fast(float x) { return 1.0f - 2.0f * fast_rcp(1.0f + __expf(2.0f * x)); }

// W_eff[i][c] = sum_j W_fc1[j,i] * W_fc2[c,j];  b_eff[c] = b_fc2[c] + sum_j b_fc1[j]*W_fc2[c,j]
__global__ void prep_weff(const float* __restrict__ Wfc1, const float* __restrict__ bfc1,
                          const float* __restrict__ Wfc2, const float* __restrict__ bfc2,
                          float* __restrict__ ws) {
  int i = blockIdx.x * blockDim.x + threadIdx.x;
  if (i < THn) {
    float s0a = 0.f, s1a = 0.f, s0b = 0.f, s1b = 0.f;
    float s0c = 0.f, s1c = 0.f, s0d = 0.f, s1d = 0.f;
#pragma unroll 4
    for (int j = 0; j < FC1n; j += 4) {
      float wa = Wfc1[(j + 0) * THn + i];
      float wb = Wfc1[(j + 1) * THn + i];
      float wc = Wfc1[(j + 2) * THn + i];
      float wd = Wfc1[(j + 3) * THn + i];
      s0a = fmaf(wa, Wfc2[j + 0], s0a); s1a = fmaf(wa, Wfc2[FC1n + j + 0], s1a);
      s0b = fmaf(wb, Wfc2[j + 1], s0b); s1b = fmaf(wb, Wfc2[FC1n + j + 1], s1b);
      s0c = fmaf(wc, Wfc2[j + 2], s0c); s1c = fmaf(wc, Wfc2[FC1n + j + 2], s1c);
      s0d = fmaf(wd, Wfc2[j + 3], s0d); s1d = fmaf(wd, Wfc2[FC1n + j + 3], s1d);
    }
    ws[i * 2 + 0] = (s0a + s0b) + (s0c + s0d);
    ws[i * 2 + 1] = (s1a + s1b) + (s1c + s1d);
  } else if (i < THn + 2) {
    int c = i - THn;
    float s = bfc2[c];
    for (int j = 0; j < FC1n; ++j) s = fmaf(bfc1[j], Wfc2[c * FC1n + j], s);
    ws[2 * THn + c] = s;
  }
}

__global__ __launch_bounds__(256) void gru_scan(
    const float* __restrict__ x,
    const float* __restrict__ Wih0, const float* __restrict__ Whh0,
    const float* __restrict__ bih0, const float* __restrict__ bhh0,
    const float* __restrict__ Wih1, const float* __restrict__ Whh1,
    const float* __restrict__ bih1, const float* __restrict__ bhh1,
    const float* __restrict__ ws, float* __restrict__ y) {
  __shared__ float weff[2 * THn];
  __shared__ __align__(16) float xstage[4][2][Ff];  // per-wave double buffer, 224B each
  for (int idx = threadIdx.x; idx < 2 * THn; idx += 256) weff[idx] = ws[idx];
  __syncthreads();

  const int lane = threadIdx.x & 63;
  const int wv = threadIdx.x >> 6;
  const int b = blockIdx.x * 4 + wv;
  const int g = (lane < Gg) ? lane : 0;  // idle lanes 60..63 replicate row 0 (harmless)

  // register-resident weight rows for this lane's gate
  float wih0[Ff], whh0[Hh], wih1[Hh], whh1[Hh];
#pragma unroll
  for (int f = 0; f < Ff; ++f) wih0[f] = Wih0[g * Ff + f];
#pragma unroll
  for (int k = 0; k < Hh; ++k) whh0[k] = Whh0[g * Hh + k];
#pragma unroll
  for (int k = 0; k < Hh; ++k) wih1[k] = Wih1[g * Hh + k];
#pragma unroll
  for (int k = 0; k < Hh; ++k) whh1[k] = Whh1[g * Hh + k];
  const float bi0 = bih0[g], bh0 = bhh0[g], bi1 = bih1[g], bh1 = bhh1[g];

  // broadcast h-state (readlane -> SGPR) + per-lane owned h (lane 40+j owns h[j])
  float sA[Hh], sB[Hh];
#pragma unroll
  for (int k = 0; k < Hh; ++k) { sA[k] = 0.f; sB[k] = 0.f; }
  float hmA = 0.f, hmB = 0.f, y0 = 0.f, y1 = 0.f;

  const float* xrow = x + (size_t)b * (Tt * Ff);
  // precomputed ds_bpermute byte addresses (r from lane j, z from lane 20+j)
  const int addrR = ((lane >= 40) ? (lane - 40) : lane) * 4;
  const int addrZ = ((lane >= 40) ? (lane - 20) : lane) * 4;
  const int jm = (lane >= 40 && lane < Gg) ? lane - 40 : 0;

  // prologue: stage row 0 into buffer 0 (lanes 0..13 each provide 16B)
  if (lane < 14) {
    __builtin_amdgcn_global_load_lds((gas_uchar*)(xrow + lane * 4),
                                     (las_uchar*)&xstage[wv][0][0], 16, 0, 0);
  }

#pragma unroll 1
  for (int t = 0; t < Tt; ++t) {
    // prefetch row t+1 (clamped at the end: re-stage row 55, never consumed)
    const float* nxt = xrow + ((t < Tt - 1) ? Ff : 0);
    if (lane < 14) {
      __builtin_amdgcn_global_load_lds((gas_uchar*)(nxt + lane * 4),
                                       (las_uchar*)&xstage[wv][(t + 1) & 1][0], 16, 0, 0);
    }
    // wait until only the newest staging load is outstanding -> row t landed
    asm volatile("s_waitcnt vmcnt(1)" ::: "memory");
    const float4* xs = (const float4*)&xstage[wv][t & 1][0];

    // ---- layer 0 ----
    {
      float a0 = bi0, a1 = 0.f, a2 = 0.f, a3 = 0.f;
#pragma unroll
      for (int i = 0; i < 14; ++i) {
        float4 xv = xs[i];  // uniform-address ds_read_b128 (broadcast)
        a0 = fmaf(xv.x, wih0[4 * i + 0], a0);
        a1 = fmaf(xv.y, wih0[4 * i + 1], a1);
        a2 = fmaf(xv.z, wih0[4 * i + 2], a2);
        a3 = fmaf(xv.w, wih0[4 * i + 3], a3);
      }
      float ig = (a0 + a1) + (a2 + a3);
      float h0 = bh0, h1v = 0.f;
#pragma unroll
      for (int k = 0; k < Hh; k += 2) {
        h0 = fmaf(sA[k + 0], whh0[k + 0], h0);
        h1v = fmaf(sA[k + 1], whh0[k + 1], h1v);
      }
      float hg = h0 + h1v;
      float sg = sigmoid_fast(ig + hg);  // r on lanes 0..19, z on 20..39
      float rr = __uint_as_float(__builtin_amdgcn_ds_bpermute(addrR, __float_as_uint(sg)));
      float nn = tanh_fast(fmaf(rr, hg, ig));  // meaningful on lanes 40..59
      float zz = __uint_as_float(__builtin_amdgcn_ds_bpermute(addrZ, __float_as_uint(sg)));
      hmA = fmaf(zz, hmA - nn, nn);  // n + z*(h-n)
#pragma unroll
      for (int j = 0; j < Hh; ++j) sA[j] = rdlane(hmA, 40 + j);
    }
    // ---- layer 1 ----
    {
      float a0 = bi1, a1 = 0.f;
#pragma unroll
      for (int k = 0; k < Hh; k += 2) {
        a0 = fmaf(sA[k + 0], wih1[k + 0], a0);
        a1 = fmaf(sA[k + 1], wih1[k + 1], a1);
      }
      float ig = a0 + a1;
      float h0 = bh1, h1v = 0.f;
#pragma unroll
      for (int k = 0; k < Hh; k += 2) {
        h0 = fmaf(sB[k + 0], whh1[k + 0], h0);
        h1v = fmaf(sB[k + 1], whh1[k + 1], h1v);
      }
      float hg = h0 + h1v;
      float sg = sigmoid_fast(ig + hg);
      float rr = __uint_as_float(__builtin_amdgcn_ds_bpermute(addrR, __float_as_uint(sg)));
      float nn = tanh_fast(fmaf(rr, hg, ig));
      float zz = __uint_as_float(__builtin_amdgcn_ds_bpermute(addrZ, __float_as_uint(sg)));
      hmB = fmaf(zz, hmB - nn, nn);
#pragma unroll
      for (int j = 0; j < Hh; ++j) sB[j] = rdlane(hmB, 40 + j);
    }
    // ---- FC accumulation (lane 40+j holds h2[t][j]) ----
    {
      float2 wv2 = *(const float2*)&weff[(t * Hh + jm) * 2];
      y0 = fmaf(hmB, wv2.x, y0);
      y1 = fmaf(hmB, wv2.y, y1);
    }
    xrow += Ff;
  }

  // reduce the 20 n-lanes' partial FC sums across the wave
  if (!(lane >= 40 && lane < Gg)) { y0 = 0.f; y1 = 0.f; }
#pragma unroll
  for (int off = 32; off >= 1; off >>= 1) {
    y0 += __shfl_xor(y0, off, 64);
    y1 += __shfl_xor(y1, off, 64);
  }
  if (lane == 0) {
    float be0 = ws[2 * THn + 0], be1 = ws[2 * THn + 1];
    float2 out = make_float2(y0 + be0, y1 + be1);
    *(float2*)(y + (size_t)b * 2) = out;
  }
}

extern "C" void kernel_launch(void* const* d_in, const int* in_sizes, int n_in,
                              void* d_out, int out_size, void* d_ws, size_t ws_size,
                              hipStream_t stream) {
  const float* x    = (const float*)d_in[0];
  const float* Wih0 = (const float*)d_in[1];
  const float* Whh0 = (const float*)d_in[2];
  const float* bih0 = (const float*)d_in[3];
  const float* bhh0 = (const float*)d_in[4];
  const float* Wih1 = (const float*)d_in[5];
  const float* Whh1 = (const float*)d_in[6];
  const float* bih1 = (const float*)d_in[7];
  const float* bhh1 = (const float*)d_in[8];
  const float* Wfc1 = (const float*)d_in[9];
  const float* bfc1 = (const float*)d_in[10];
  const float* Wfc2 = (const float*)d_in[11];
  const float* bfc2 = (const float*)d_in[12];
  float* ws = (float*)d_ws;   // [2*1120 W_eff + 2 b_eff] floats
  float* y  = (float*)d_out;  // [16384, 2]

  prep_weff<<<9, 128, 0, stream>>>(Wfc1, bfc1, Wfc2, bfc2, ws);
  gru_scan<<<Bsz / 4, 256, 0, stream>>>(x, Wih0, Whh0, bih0, bhh0,
                                        Wih1, Whh1, bih1, bhh1, ws, y);
}